// Round 2
// baseline (135.868 us; speedup 1.0000x reference)
//
#include <hip/hip_runtime.h>

#define NP 8192
#define CAP 16
#define NCG 20
#define NC3 8000      // 20^3 cells of size 1.0 over [0,20)^3
#define ECAP 16384    // CSR entry capacity (expected total ~8800)

// ---------- binning (counting sort of occupied pred points into cells) ----------

__global__ void zero_counts(int* __restrict__ cellcnt) {
    int i = blockIdx.x * 256 + threadIdx.x;
    if (i < NC3) cellcnt[i] = 0;
}

__global__ void bin_count(const float4* __restrict__ pred,
                          int* __restrict__ cellcnt,
                          int* __restrict__ pcell,
                          int* __restrict__ prank) {
    int i = blockIdx.x * 256 + threadIdx.x;
    if (i >= NP) return;
    float4 p = pred[i];
    if (p.w < 0.5f) { pcell[i] = -1; return; }
    int cx = min((int)p.x, NCG - 1);
    int cy = min((int)p.y, NCG - 1);
    int cz = min((int)p.z, NCG - 1);
    int c = (cz * NCG + cy) * NCG + cx;
    pcell[i] = c;
    prank[i] = atomicAdd(&cellcnt[c], 1);
}

__global__ __launch_bounds__(1024)
void scan_cells(const int* __restrict__ cellcnt, int* __restrict__ cellstart) {
    __shared__ int ss[1024];
    int tid = threadIdx.x;
    int base = tid * 8;
    int loc[8]; int s = 0;
    #pragma unroll
    for (int k = 0; k < 8; ++k) {
        int c = base + k;
        int v = (c < NC3) ? cellcnt[c] : 0;
        loc[k] = s; s += v;
    }
    ss[tid] = s; __syncthreads();
    for (int off = 1; off < 1024; off <<= 1) {
        int t = (tid >= off) ? ss[tid - off] : 0;
        __syncthreads();
        ss[tid] += t;
        __syncthreads();
    }
    int eb = ss[tid] - s;
    #pragma unroll
    for (int k = 0; k < 8; ++k) {
        int c = base + k;
        if (c < NC3) cellstart[c] = eb + loc[k];
    }
    if (tid == 1023) cellstart[NC3] = ss[1023];
}

__global__ void scatter_pred(const float4* __restrict__ pred,
                             const int* __restrict__ pcell,
                             const int* __restrict__ prank,
                             const int* __restrict__ cellstart,
                             float4* __restrict__ spred,
                             int* __restrict__ sidx) {
    int i = blockIdx.x * 256 + threadIdx.x;
    if (i >= NP) return;
    int c = pcell[i];
    if (c < 0) return;
    int slot = cellstart[c] + prank[i];
    spred[slot] = pred[i];
    sidx[slot] = i;
}

// ---------- candidate build: one thread per true row, 27-cell neighborhood ----------

__global__ void build_cands(const float4* __restrict__ truec,
                            const float4* __restrict__ spred,
                            const int* __restrict__ sidx,
                            const int* __restrict__ cellstart,
                            int* __restrict__ cnt,
                            int* __restrict__ cj,
                            float* __restrict__ cd) {
    int i = blockIdx.x * 256 + threadIdx.x;
    if (i >= NP) return;
    float4 t = truec[i];
    int n = 0;
    float sd[CAP]; int sj[CAP];
    if (t.w >= 0.5f) {
        int cx = min((int)t.x, NCG - 1);
        int cy = min((int)t.y, NCG - 1);
        int cz = min((int)t.z, NCG - 1);
        int z0 = max(cz - 1, 0), z1 = min(cz + 1, NCG - 1);
        int y0 = max(cy - 1, 0), y1 = min(cy + 1, NCG - 1);
        int x0 = max(cx - 1, 0), x1 = min(cx + 1, NCG - 1);
        for (int zz = z0; zz <= z1; ++zz) {
            for (int yy = y0; yy <= y1; ++yy) {
                int cb = (zz * NCG + yy) * NCG;
                int s0 = cellstart[cb + x0];
                int s1 = cellstart[cb + x1 + 1];   // x-contiguous span
                for (int s = s0; s < s1; ++s) {
                    float4 p = spred[s];
                    float dx = t.x - p.x, dy = t.y - p.y, dz = t.z - p.z;
                    float d = sqrtf(dx * dx + dy * dy + dz * dz);
                    if (d <= 1.0f) {
                        int j = sidx[s];
                        if (n < CAP) {
                            int b = n - 1;
                            while (b >= 0 && (sd[b] > d || (sd[b] == d && sj[b] > j))) {
                                sd[b + 1] = sd[b]; sj[b + 1] = sj[b]; --b;
                            }
                            sd[b + 1] = d; sj[b + 1] = j; ++n;
                        } else if (sd[CAP - 1] > d ||
                                   (sd[CAP - 1] == d && sj[CAP - 1] > j)) {
                            int b = CAP - 2;
                            while (b >= 0 && (sd[b] > d || (sd[b] == d && sj[b] > j))) {
                                sd[b + 1] = sd[b]; sj[b + 1] = sj[b]; --b;
                            }
                            sd[b + 1] = d; sj[b + 1] = j;
                        }
                    }
                }
            }
        }
    }
    cnt[i] = n;
    for (int k = 0; k < n; ++k) {
        cj[i * CAP + k] = sj[k];
        cd[i * CAP + k] = sd[k];
    }
}

// ---------- matching (Jacobi deferred acceptance, all-LDS CSR) + reduction ----------

__global__ __launch_bounds__(1024)
void match_reduce(const float4* __restrict__ pred,
                  const float4* __restrict__ truec,
                  const int* __restrict__ cnt,
                  const int* __restrict__ cj,
                  const float* __restrict__ cd,
                  float* __restrict__ out) {
    __shared__ int ss[1024];
    __shared__ int off[NP + 1];          // 32KB CSR offsets
    __shared__ unsigned short E[ECAP];   // 32KB candidate col indices
    __shared__ int H[NP];                // 32KB col -> lowest chooser row
    __shared__ unsigned char C[NP];      // 8KB  row -> chosen list position
    __shared__ int changed;
    __shared__ float redf[2][16];
    __shared__ int redi[2][16];
    int tid = threadIdx.x;
    int base = tid * 8;

    // CSR offsets via block scan of cnt
    int loc[8]; int s = 0;
    #pragma unroll
    for (int k = 0; k < 8; ++k) { int v = cnt[base + k]; loc[k] = s; s += v; }
    ss[tid] = s; __syncthreads();
    for (int o = 1; o < 1024; o <<= 1) {
        int t = (tid >= o) ? ss[tid - o] : 0;
        __syncthreads();
        ss[tid] += t;
        __syncthreads();
    }
    int eb = ss[tid] - s;
    #pragma unroll
    for (int k = 0; k < 8; ++k) off[base + k] = eb + loc[k];
    if (tid == 1023) off[NP] = ss[1023];
    for (int r = tid; r < NP; r += 1024) { H[r] = 0x7FFFFFFF; C[r] = 0xFF; }
    __syncthreads();

    // fill entries
    for (int r = base; r < base + 8; ++r) {
        int o0 = off[r], n = off[r + 1] - o0;
        for (int k = 0; k < n; ++k) {
            int e = o0 + k;
            if (e < ECAP) E[e] = (unsigned short)cj[r * CAP + k];
        }
    }
    __syncthreads();

    // Jacobi rounds; fixed point == serial greedy matching of the reference
    for (int it = 0; it < NP; ++it) {
        if (tid == 0) changed = 0;
        __syncthreads();
        for (int r = base; r < base + 8; ++r) {
            int o0 = off[r], o1 = off[r + 1];
            if (o0 == o1) continue;
            int pick = 0xFF;
            for (int e = o0; e < o1; ++e) {
                if (H[E[e]] >= r) { pick = e - o0; break; }
            }
            if ((unsigned char)pick != C[r]) { C[r] = (unsigned char)pick; changed = 1; }
        }
        __syncthreads();
        if (!changed) break;
        for (int r = tid; r < NP; r += 1024) H[r] = 0x7FFFFFFF;
        __syncthreads();
        for (int r = base; r < base + 8; ++r) {
            unsigned char p = C[r];
            if (p != 0xFF) atomicMin(&H[E[off[r] + p]], r);
        }
        __syncthreads();
    }

    // final reduction
    float sdist = 0.f, sprob = 0.f;
    int nm = 0, nocc = 0;
    for (int r = tid; r < NP; r += 1024) {
        float tp = truec[r].w;
        if (tp >= 0.5f) ++nocc;
        unsigned char p = C[r];
        if (p != 0xFF) {
            ++nm;
            sdist += cd[r * CAP + p];
            int j = cj[r * CAP + p];
            float dp = tp - pred[j].w;
            sprob += dp * dp;
        }
    }
    for (int o = 32; o; o >>= 1) {
        sdist += __shfl_down(sdist, o);
        sprob += __shfl_down(sprob, o);
        nm    += __shfl_down(nm, o);
        nocc  += __shfl_down(nocc, o);
    }
    int wave = tid >> 6, lane = tid & 63;
    if (lane == 0) {
        redf[0][wave] = sdist; redf[1][wave] = sprob;
        redi[0][wave] = nm;    redi[1][wave] = nocc;
    }
    __syncthreads();
    if (tid == 0) {
        float S = 0.f, P = 0.f; int NM = 0, NO = 0;
        for (int w = 0; w < 16; ++w) {
            S += redf[0][w]; P += redf[1][w];
            NM += redi[0][w]; NO += redi[1][w];
        }
        float nmf = (float)NM;
        float unm = (float)NO - nmf;
        out[0] = (S / nmf + 10.0f * unm) + (P / nmf + unm);
    }
}

extern "C" void kernel_launch(void* const* d_in, const int* in_sizes, int n_in,
                              void* d_out, int out_size, void* d_ws, size_t ws_size,
                              hipStream_t stream) {
    const float4* pred  = (const float4*)d_in[0];
    const float4* truec = (const float4*)d_in[1];
    float* out = (float*)d_out;

    float4* spred   = (float4*)d_ws;               // NP float4 (16B aligned first)
    int* cellcnt    = (int*)(spred + NP);          // NC3
    int* cellstart  = cellcnt + NC3;               // NC3+1
    int* pcell      = cellstart + NC3 + 1;         // NP
    int* prank      = pcell + NP;                  // NP
    int* sidx       = prank + NP;                  // NP
    int* cnt        = sidx + NP;                   // NP
    int* cj         = cnt + NP;                    // NP*CAP
    float* cd       = (float*)(cj + (size_t)NP * CAP);

    zero_counts <<<32, 256, 0, stream>>>(cellcnt);
    bin_count   <<<32, 256, 0, stream>>>(pred, cellcnt, pcell, prank);
    scan_cells  <<<1, 1024, 0, stream>>>(cellcnt, cellstart);
    scatter_pred<<<32, 256, 0, stream>>>(pred, pcell, prank, cellstart, spred, sidx);
    build_cands <<<32, 256, 0, stream>>>(truec, spred, sidx, cellstart, cnt, cj, cd);
    match_reduce<<<1, 1024, 0, stream>>>(pred, truec, cnt, cj, cd, out);
}

// Round 3
// 61.221 us; speedup vs baseline: 2.2193x; 2.2193x over previous
//
#include <hip/hip_runtime.h>

#define NP 8192
#define CAP 16
#define NCG 20
#define NC3 8000        // 20^3 unit cells over [0,20)^3
#define ECAP 16384      // CSR entry capacity (expected total ~8800)
#define WCAP 6144       // worklist capacity (max ~3600 initial)
#define INF_I 0x7FFFFFFF

// ---------- Kernel 1: fused binning (zero + count + scan + scatter), 1 block ----------
__global__ __launch_bounds__(1024)
void bin_all(const float4* __restrict__ pred,
             int* __restrict__ gstart,      // NC3+1 cell start offsets (global, for build_cands)
             float4* __restrict__ spred,    // occupied pred, cell-sorted
             int* __restrict__ sidx) {      // original indices
    __shared__ int cc[NC3 + 1];
    __shared__ int ss[1024];
    int tid = threadIdx.x;

    #pragma unroll
    for (int k = 0; k < 8; ++k) {
        int c = tid * 8 + k;
        if (c <= NC3) cc[c] = 0;
    }
    __syncthreads();

    float4 p[8]; int cell[8], rk[8];
    #pragma unroll
    for (int k = 0; k < 8; ++k) {
        int i = k * 1024 + tid;
        p[k] = pred[i];
        if (p[k].w >= 0.5f) {
            int cx = min((int)p[k].x, NCG - 1);
            int cy = min((int)p[k].y, NCG - 1);
            int cz = min((int)p[k].z, NCG - 1);
            cell[k] = (cz * NCG + cy) * NCG + cx;
            rk[k] = atomicAdd(&cc[cell[k]], 1);
        } else cell[k] = -1;
    }
    __syncthreads();

    // exclusive scan of cc[0..NC3) in place (each thread owns 8 contiguous cells)
    int base = tid * 8;
    int loc[8]; int s = 0;
    #pragma unroll
    for (int k = 0; k < 8; ++k) {
        int c = base + k;
        int v = (c < NC3) ? cc[c] : 0;
        loc[k] = s; s += v;
    }
    ss[tid] = s; __syncthreads();
    for (int o = 1; o < 1024; o <<= 1) {
        int t = (tid >= o) ? ss[tid - o] : 0;
        __syncthreads();
        ss[tid] += t;
        __syncthreads();
    }
    int eb = ss[tid] - s;
    #pragma unroll
    for (int k = 0; k < 8; ++k) {
        int c = base + k;
        if (c < NC3) { int v = eb + loc[k]; cc[c] = v; gstart[c] = v; }
    }
    if (tid == 1023) gstart[NC3] = ss[1023];
    __syncthreads();

    #pragma unroll
    for (int k = 0; k < 8; ++k) {
        if (cell[k] >= 0) {
            int slot = cc[cell[k]] + rk[k];
            spred[slot] = p[k];
            sidx[slot] = k * 1024 + tid;
        }
    }
}

// ---------- Kernel 2: candidate build, 4 lanes per true row, LDS lists ----------
__global__ __launch_bounds__(256)
void build_cands(const float4* __restrict__ truec,
                 const float4* __restrict__ spred,
                 const int* __restrict__ sidx,
                 const int* __restrict__ gstart,
                 int* __restrict__ cnt,
                 int* __restrict__ cj,
                 float* __restrict__ cd) {
    __shared__ unsigned long long skey[64][CAP];
    __shared__ int scnt[64];
    int tid = threadIdx.x;
    int l = tid & 3, g = tid >> 2;
    int i = blockIdx.x * 64 + g;
    if (l == 0) scnt[g] = 0;
    __syncthreads();

    float4 t = truec[i];
    if (t.w >= 0.5f) {
        int cx = min((int)t.x, NCG - 1);
        int cy = min((int)t.y, NCG - 1);
        int cz = min((int)t.z, NCG - 1);
        int x0 = max(cx - 1, 0), x1 = min(cx + 1, NCG - 1);
        for (int sp = l; sp < 9; sp += 4) {
            int zz = cz - 1 + sp / 3;
            int yy = cy - 1 + sp % 3;
            if (zz < 0 || zz >= NCG || yy < 0 || yy >= NCG) continue;
            int cb = (zz * NCG + yy) * NCG;
            int s0 = gstart[cb + x0];
            int s1 = gstart[cb + x1 + 1];
            for (int s = s0; s < s1; ++s) {
                float4 p = spred[s];
                float dx = t.x - p.x, dy = t.y - p.y, dz = t.z - p.z;
                float d = sqrtf(dx * dx + dy * dy + dz * dz);
                if (d <= 1.0f) {
                    int k = atomicAdd(&scnt[g], 1);
                    if (k < CAP)
                        skey[g][k] = ((unsigned long long)__float_as_uint(d) << 32)
                                     | (unsigned int)sidx[s];
                }
            }
        }
    }
    __syncthreads();
    int n = min(scnt[g], CAP);
    if (l == 0 && n > 1) {
        // insertion sort (LDS, ascending u64 key = (d asc, j asc))
        for (int a = 1; a < n; ++a) {
            unsigned long long kv = skey[g][a];
            int b = a - 1;
            while (b >= 0 && skey[g][b] > kv) { skey[g][b + 1] = skey[g][b]; --b; }
            skey[g][b + 1] = kv;
        }
    }
    __syncthreads();
    for (int k = l; k < n; k += 4) {
        unsigned long long kv = skey[g][k];
        cj[i * CAP + k] = (int)(kv & 0xFFFFFFFFu);
        cd[i * CAP + k] = __uint_as_float((unsigned int)(kv >> 32));
    }
    if (l == 0) cnt[i] = n;
}

// ---------- Kernel 3: event-driven Gale-Shapley matching + reduction, 1 block ----------
__global__ __launch_bounds__(1024)
void match_reduce(const float4* __restrict__ pred,
                  const float4* __restrict__ truec,
                  const int* __restrict__ cnt,
                  const int* __restrict__ cj,
                  const float* __restrict__ cd,
                  float* __restrict__ out) {
    __shared__ int ss[1024];                  // 4KB scan temp
    __shared__ unsigned short offu[NP + 1];   // 16KB CSR offsets
    __shared__ unsigned short E[ECAP];        // 32KB candidate cols
    __shared__ int H[NP];                     // 32KB col -> holder row
    __shared__ unsigned char ptrr[NP];        // 8KB row scan pointer
    __shared__ unsigned short wl[2][WCAP];    // 24KB worklists
    __shared__ int wcnt[2];
    __shared__ float redf[2][16];
    __shared__ int redi[2][16];
    int tid = threadIdx.x;
    int base = tid * 8;

    if (tid == 0) { wcnt[0] = 0; wcnt[1] = 0; }
    for (int r = tid; r < NP; r += 1024) { H[r] = INF_I; ptrr[r] = 0; }

    // CSR offsets via block scan of cnt (each thread owns 8 contiguous rows)
    int loc[8]; int s = 0;
    #pragma unroll
    for (int k = 0; k < 8; ++k) { int v = cnt[base + k]; loc[k] = s; s += v; }
    ss[tid] = s; __syncthreads();
    for (int o = 1; o < 1024; o <<= 1) {
        int t = (tid >= o) ? ss[tid - o] : 0;
        __syncthreads();
        ss[tid] += t;
        __syncthreads();
    }
    int eb = ss[tid] - s;
    #pragma unroll
    for (int k = 0; k < 8; ++k) offu[base + k] = (unsigned short)(eb + loc[k]);
    if (tid == 1023) offu[NP] = (unsigned short)ss[1023];
    __syncthreads();

    // fill CSR entries + initial worklist
    for (int r = base; r < base + 8; ++r) {
        int o0 = offu[r], n = offu[r + 1] - o0;
        for (int k = 0; k < n; ++k) {
            int e = o0 + k;
            if (e < ECAP) E[e] = (unsigned short)cj[r * CAP + k];
        }
        if (n > 0) {
            int w = atomicAdd(&wcnt[0], 1);
            if (w < WCAP) wl[0][w] = (unsigned short)r;
        }
    }
    __syncthreads();

    // event-driven deferred acceptance: fixed point == reference serial greedy
    int cu = 0;
    for (int round = 0; round < 4096; ++round) {
        int nwork = wcnt[cu];
        if (nwork == 0) break;
        if (tid == 0) wcnt[cu ^ 1] = 0;
        __syncthreads();
        for (int idx = tid; idx < nwork; idx += 1024) {
            int r = wl[cu][idx];
            int o0 = offu[r], o1 = offu[r + 1];
            int p = ptrr[r];
            while (o0 + p < o1) {
                int e = o0 + p;
                if (e >= ECAP) { p = o1 - o0; break; }
                int col = E[e];
                if (H[col] < r) { ++p; continue; }     // permanent rejection (H only decreases)
                int old = atomicMin(&H[col], r);
                if (old > r) {                          // acquired col
                    if (old != INF_I) {                 // displaced previous holder
                        int w = atomicAdd(&wcnt[cu ^ 1], 1);
                        if (w < WCAP) wl[cu ^ 1][w] = (unsigned short)old;
                    }
                    break;
                }
                ++p;                                    // lost the race to a better row
            }
            ptrr[r] = (unsigned char)p;
        }
        __syncthreads();
        cu ^= 1;
    }

    // final reduction
    float sdist = 0.f, sprob = 0.f;
    int nm = 0, nocc = 0;
    for (int r = tid; r < NP; r += 1024) {
        float tp = truec[r].w;
        if (tp >= 0.5f) ++nocc;
        int o0 = offu[r], n = offu[r + 1] - o0;
        int p = ptrr[r];
        if (p < n && H[E[o0 + p]] == r) {
            int j = E[o0 + p];
            ++nm;
            sdist += cd[r * CAP + p];
            float dp = tp - pred[j].w;
            sprob += dp * dp;
        }
    }
    for (int o = 32; o; o >>= 1) {
        sdist += __shfl_down(sdist, o);
        sprob += __shfl_down(sprob, o);
        nm    += __shfl_down(nm, o);
        nocc  += __shfl_down(nocc, o);
    }
    int wave = tid >> 6, lane = tid & 63;
    if (lane == 0) {
        redf[0][wave] = sdist; redf[1][wave] = sprob;
        redi[0][wave] = nm;    redi[1][wave] = nocc;
    }
    __syncthreads();
    if (tid == 0) {
        float S = 0.f, P = 0.f; int NM = 0, NO = 0;
        for (int w = 0; w < 16; ++w) {
            S += redf[0][w]; P += redf[1][w];
            NM += redi[0][w]; NO += redi[1][w];
        }
        float nmf = (float)NM;
        float unm = (float)NO - nmf;
        out[0] = (S / nmf + 10.0f * unm) + (P / nmf + unm);
    }
}

extern "C" void kernel_launch(void* const* d_in, const int* in_sizes, int n_in,
                              void* d_out, int out_size, void* d_ws, size_t ws_size,
                              hipStream_t stream) {
    const float4* pred  = (const float4*)d_in[0];
    const float4* truec = (const float4*)d_in[1];
    float* out = (float*)d_out;

    float4* spred = (float4*)d_ws;                 // NP float4
    int* gstart   = (int*)(spred + NP);            // NC3+1
    int* sidx     = gstart + NC3 + 1;              // NP
    int* cnt      = sidx + NP;                     // NP
    int* cj       = cnt + NP;                      // NP*CAP
    float* cd     = (float*)(cj + (size_t)NP * CAP);

    bin_all     <<<1,   1024, 0, stream>>>(pred, gstart, spred, sidx);
    build_cands <<<128, 256,  0, stream>>>(truec, spred, sidx, gstart, cnt, cj, cd);
    match_reduce<<<1,   1024, 0, stream>>>(pred, truec, cnt, cj, cd, out);
}

// Round 4
// 42.550 us; speedup vs baseline: 3.1931x; 1.4388x over previous
//
#include <hip/hip_runtime.h>

#define NP 8192
#define CAP 16
#define NCG 20
#define NC3 8000        // 20^3 unit cells over [0,20)^3
#define ECAP 16384      // CSR entry capacity (expected total ~8800)
#define INF_U 0xFFFFFFFFu

// ---------- Kernel 1: fused binning (zero + count + scan + scatter), 1 block ----------
__global__ __launch_bounds__(1024)
void bin_all(const float4* __restrict__ pred,
             int* __restrict__ gstart,      // NC3+1 cell starts
             float4* __restrict__ spred,    // occupied pred, cell-sorted
             int* __restrict__ sidx,        // original indices
             int* __restrict__ ecnt) {      // global CSR entry allocator (zeroed here)
    __shared__ int cc[NC3];
    __shared__ int wt[16];
    int tid = threadIdx.x;
    int lane = tid & 63, wave = tid >> 6;
    if (tid == 0) *ecnt = 0;
    #pragma unroll
    for (int k = 0; k < 8; ++k) {
        int c = tid * 8 + k;
        if (c < NC3) cc[c] = 0;
    }
    __syncthreads();

    float4 p[8]; int cell[8], rk[8];
    #pragma unroll
    for (int k = 0; k < 8; ++k) {
        int i = k * 1024 + tid;
        p[k] = pred[i];
        if (p[k].w >= 0.5f) {
            int cx = min((int)p[k].x, NCG - 1);
            int cy = min((int)p[k].y, NCG - 1);
            int cz = min((int)p[k].z, NCG - 1);
            cell[k] = (cz * NCG + cy) * NCG + cx;
            rk[k] = atomicAdd(&cc[cell[k]], 1);
        } else cell[k] = -1;
    }
    __syncthreads();

    // exclusive scan over NC3 cells: per-thread serial(8) + wave shfl scan + 16-wave combine
    int base = tid * 8;
    int loc[8]; int s = 0;
    #pragma unroll
    for (int k = 0; k < 8; ++k) {
        int c = base + k;
        int v = (c < NC3) ? cc[c] : 0;
        loc[k] = s; s += v;
    }
    int inc = s;
    #pragma unroll
    for (int o = 1; o < 64; o <<= 1) {
        int t = __shfl_up(inc, o);
        if (lane >= o) inc += t;
    }
    if (lane == 63) wt[wave] = inc;
    __syncthreads();
    if (tid < 16) {
        int v = wt[tid]; int iv = v;
        #pragma unroll
        for (int o = 1; o < 16; o <<= 1) {
            int t = __shfl_up(iv, o);
            if (tid >= o) iv += t;
        }
        wt[tid] = iv - v;   // exclusive wave base
    }
    __syncthreads();
    int eb = wt[wave] + inc - s;
    #pragma unroll
    for (int k = 0; k < 8; ++k) {
        int c = base + k;
        if (c < NC3) { int v = eb + loc[k]; cc[c] = v; gstart[c] = v; }
    }
    if (tid == 1023) gstart[NC3] = wt[15] + inc;
    __syncthreads();

    #pragma unroll
    for (int k = 0; k < 8; ++k) {
        if (cell[k] >= 0) {
            int slot = cc[cell[k]] + rk[k];
            spred[slot] = p[k];
            sidx[slot] = k * 1024 + tid;
        }
    }
}

// ---------- Kernel 2: candidate build + direct CSR emission ----------
// 4 lanes per true row; per-row list sorted by (d asc, j asc) via packed u64 key.
// Block allocates one contiguous CSR segment via a single global atomicAdd.
__global__ __launch_bounds__(256)
void build_cands(const float4* __restrict__ truec,
                 const float4* __restrict__ spred,
                 const int* __restrict__ sidx,
                 const int* __restrict__ gstart,
                 int* __restrict__ ecnt,
                 unsigned int* __restrict__ desc,     // (start<<5)|n per row
                 unsigned short* __restrict__ Eg) {   // entry cols, sorted per row
    __shared__ unsigned long long skey[64][CAP];
    __shared__ int scnt[64];
    __shared__ int srow[64];
    int tid = threadIdx.x;
    int l = tid & 3, g = tid >> 2;
    int i = blockIdx.x * 64 + g;
    if (l == 0) scnt[g] = 0;
    __syncthreads();

    float4 t = truec[i];
    if (t.w >= 0.5f) {
        int cx = min((int)t.x, NCG - 1);
        int cy = min((int)t.y, NCG - 1);
        int cz = min((int)t.z, NCG - 1);
        int x0 = max(cx - 1, 0), x1 = min(cx + 1, NCG - 1);
        for (int sp = l; sp < 9; sp += 4) {
            int zz = cz - 1 + sp / 3;
            int yy = cy - 1 + sp % 3;
            if (zz < 0 || zz >= NCG || yy < 0 || yy >= NCG) continue;
            int cb = (zz * NCG + yy) * NCG;
            int s0 = gstart[cb + x0];
            int s1 = gstart[cb + x1 + 1];
            for (int s = s0; s < s1; ++s) {
                float4 p = spred[s];
                float dx = t.x - p.x, dy = t.y - p.y, dz = t.z - p.z;
                float d = sqrtf(dx * dx + dy * dy + dz * dz);
                if (d <= 1.0f) {
                    int k = atomicAdd(&scnt[g], 1);
                    if (k < CAP)
                        skey[g][k] = ((unsigned long long)__float_as_uint(d) << 32)
                                     | (unsigned int)sidx[s];
                }
            }
        }
    }
    __syncthreads();
    if (l == 0) {
        int n = min(scnt[g], CAP);
        for (int a = 1; a < n; ++a) {
            unsigned long long kv = skey[g][a];
            int b = a - 1;
            while (b >= 0 && skey[g][b] > kv) { skey[g][b + 1] = skey[g][b]; --b; }
            skey[g][b + 1] = kv;
        }
        scnt[g] = n;
    }
    __syncthreads();
    // wave 0 allocates the block's CSR segment and writes row descriptors
    if (tid < 64) {
        int n = scnt[tid];
        int inc = n;
        #pragma unroll
        for (int o = 1; o < 64; o <<= 1) {
            int u = __shfl_up(inc, o);
            if (tid >= o) inc += u;
        }
        int total = __shfl(inc, 63);
        int b = 0;
        if (tid == 0) b = atomicAdd(ecnt, total);
        b = __shfl(b, 0);
        int rowstart = b + inc - n;
        int nn = n;
        if (rowstart >= ECAP) nn = 0;
        else if (rowstart + nn > ECAP) nn = ECAP - rowstart;
        desc[blockIdx.x * 64 + tid] = ((unsigned int)rowstart << 5) | (unsigned int)nn;
        srow[tid] = rowstart;
        scnt[tid] = nn;
    }
    __syncthreads();
    int rs = srow[g], nn = scnt[g];
    for (int k = l; k < nn; k += 4)
        Eg[rs + k] = (unsigned short)(skey[g][k] & 0xFFFFu);
}

// ---------- Kernel 3: barrier-free chain-following Gale-Shapley + reduction ----------
// H[col] = (row<<4)|pos, monotone-decreasing under atomicMin. Fixed point ==
// the reference's serial greedy matching (common-priority stable matching).
__global__ __launch_bounds__(1024)
void match_reduce(const float4* __restrict__ pred,
                  const float4* __restrict__ truec,
                  const unsigned int* __restrict__ desc,
                  const unsigned short* __restrict__ Eg,
                  const int* __restrict__ ecnt,
                  float* __restrict__ out) {
    __shared__ unsigned short E[ECAP];   // 32KB
    __shared__ unsigned int D[NP];       // 32KB
    __shared__ unsigned int H[NP];       // 32KB
    __shared__ float redf[2][16];
    __shared__ int redi[2][16];
    int tid = threadIdx.x;
    int ne = *ecnt; if (ne > ECAP) ne = ECAP;
    for (int e = tid; e < ne; e += 1024) E[e] = Eg[e];
    for (int r = tid; r < NP; r += 1024) { D[r] = desc[r]; H[r] = INF_U; }
    __syncthreads();

    for (int r0 = tid; r0 < NP; r0 += 1024) {
        unsigned int dsc = D[r0];
        int r = r0;
        int p = 0;
        int n = (int)(dsc & 31u);
        int o0 = (int)(dsc >> 5);
        while (p < n) {
            int col = E[o0 + p];
            unsigned int key = ((unsigned int)r << 4) | (unsigned int)p;
            unsigned int old = atomicMin(&H[col], key);
            if (old > key) {
                if (old == INF_U) break;            // took a free col: chain ends
                r = (int)(old >> 4);                // displaced row: continue its chain
                p = (int)(old & 15u) + 1;
                unsigned int d2 = D[r];
                n = (int)(d2 & 31u);
                o0 = (int)(d2 >> 5);
            } else {
                ++p;                                // better row holds it (permanent)
            }
        }
    }
    __syncthreads();

    // reduction over cols (matched pairs live in H) + occupied-true count
    float sdist = 0.f, sprob = 0.f;
    int nm = 0, nocc = 0;
    for (int j = tid; j < NP; j += 1024) {
        float4 t4 = truec[j];
        if (t4.w >= 0.5f) ++nocc;
        unsigned int h = H[j];
        if (h != INF_U) {
            int r = (int)(h >> 4);
            float4 t = truec[r];
            float4 pp = pred[j];
            float dx = t.x - pp.x, dy = t.y - pp.y, dz = t.z - pp.z;
            sdist += sqrtf(dx * dx + dy * dy + dz * dz);
            float dp = t.w - pp.w;
            sprob += dp * dp;
            ++nm;
        }
    }
    for (int o = 32; o; o >>= 1) {
        sdist += __shfl_down(sdist, o);
        sprob += __shfl_down(sprob, o);
        nm    += __shfl_down(nm, o);
        nocc  += __shfl_down(nocc, o);
    }
    int wave = tid >> 6, lane = tid & 63;
    if (lane == 0) {
        redf[0][wave] = sdist; redf[1][wave] = sprob;
        redi[0][wave] = nm;    redi[1][wave] = nocc;
    }
    __syncthreads();
    if (tid == 0) {
        float S = 0.f, P = 0.f; int NM = 0, NO = 0;
        for (int w = 0; w < 16; ++w) {
            S += redf[0][w]; P += redf[1][w];
            NM += redi[0][w]; NO += redi[1][w];
        }
        float nmf = (float)NM;
        float unm = (float)NO - nmf;
        out[0] = (S / nmf + 10.0f * unm) + (P / nmf + unm);
    }
}

extern "C" void kernel_launch(void* const* d_in, const int* in_sizes, int n_in,
                              void* d_out, int out_size, void* d_ws, size_t ws_size,
                              hipStream_t stream) {
    const float4* pred  = (const float4*)d_in[0];
    const float4* truec = (const float4*)d_in[1];
    float* out = (float*)d_out;

    float4* spred       = (float4*)d_ws;             // NP float4
    int* gstart         = (int*)(spred + NP);        // NC3+1
    int* sidx           = gstart + NC3 + 1;          // NP
    int* ecnt           = sidx + NP;                 // 1
    unsigned int* desc  = (unsigned int*)(ecnt + 1); // NP
    unsigned short* Eg  = (unsigned short*)(desc + NP); // ECAP

    bin_all     <<<1,   1024, 0, stream>>>(pred, gstart, spred, sidx, ecnt);
    build_cands <<<128, 256,  0, stream>>>(truec, spred, sidx, gstart, ecnt, desc, Eg);
    match_reduce<<<1,   1024, 0, stream>>>(pred, truec, desc, Eg, ecnt, out);
}